// Round 7
// baseline (47.928 us; speedup 1.0000x reference)
//
#include <hip/hip_runtime.h>
#include <stdint.h>

#define HW 128
#define PLANE (HW * HW)              // 16384
#define SCALE 0.17677669529663687f   // 32^-0.5

#define VMWAIT(N) asm volatile("s_waitcnt vmcnt(" #N ")" ::: "memory")
#define FENCE() asm volatile("" ::: "memory")

// async global->LDS, 16B per lane (global src per-lane, LDS dst wave-uniform+lane*16)
__device__ __forceinline__ void dma16(const float* g, float* l) {
  __builtin_amdgcn_global_load_lds(
      (const __attribute__((address_space(1))) void*)g,
      (__attribute__((address_space(3))) void*)l, 16, 0, 0);
}

// Block = one head x 4-row tile x 128 px. Thread = 2 px (x=lane, lane+64) of
// row w (wave index), all 32 channels via 8 chunks of 4. 16 jobs: j=0..7 QK
// (k chunk j), j=8..15 PV (v chunk j-8). Triple-buffered 12KB LDS chunks
// ([ch][row 6][px 128] f32), global_load_lds DMA, counted-vmcnt pipeline with
// FENCE-pinned issue order (q-prefetch group, then DMA group, then wait —
// R6's failure was the scheduler interleaving these, breaking the ledger).
// Wait ladder re-derived with margin; ledger-simulated including store counts.
__global__ __launch_bounds__(256) void natt3x3_kernel(
    const float* __restrict__ q,
    const float* __restrict__ k,
    const float* __restrict__ v,
    float* __restrict__ out) {
  // 3 buffers of 3072 floats + 4-float guards front/back (x=-1/x=128 window
  // reads land in guards or adjacent rows: finite, masked; guards zeroed).
  __shared__ __align__(16) float lds[4 + 3 * 3072 + 4];

  const int tid  = threadIdx.x;
  const int lane = tid & 63;
  const int w    = tid >> 6;            // wave = output row in tile
  const int bid  = blockIdx.x;          // ((b*4+head)*32 + ytile)
  const int ytile = bid & 31;
  const int head  = (bid >> 5) & 3;
  const int b     = bid >> 7;
  const int y0    = ytile << 2;
  const int y     = y0 + w;
  const int xA    = lane;
  const int xB    = lane + 64;
  const size_t cb = (size_t)(b * 128 + head * 32) * PLANE;
  const float* kb = k + cb;
  const float* vb = v + cb;
  const float* qb = q + cb;

  // zero the never-staged guard floats (visible to all after first barrier)
  if (tid < 4)      lds[tid] = 0.f;
  else if (tid < 8) lds[4 + 3 * 3072 + (tid - 4)] = 0.f;

  // staging: wave w stages regions (w*3+r), r=0..2 (1KB each) = channel w,
  // rows 0..5 of the chunk. region pair (ch,row): pair=(w*3+r)*2+(lane>>5).
  int spart[3], ldso[3];
#pragma unroll
  for (int r = 0; r < 3; ++r) {
    const int pair = (w * 3 + r) * 2 + (lane >> 5);
    const int ch  = pair / 6;
    const int row = pair - ch * 6;
    int rg = y0 + row - 1;
    rg = rg < 0 ? 0 : (rg > HW - 1 ? HW - 1 : rg);   // clamp; mask fixes value
    spart[r] = ch * PLANE + rg * HW + (lane & 31) * 4;
    ldso[r]  = 4 + (w * 3 + r) * 256;
  }

  float lA[9], lB[9];
#pragma unroll
  for (int i = 0; i < 9; ++i) { lA[i] = 0.f; lB[i] = 0.f; }
  float qv[2][8];

  // ---- prologue (FENCE-pinned groups): q0 | dmaK0->buf0 | dmaK1->buf1 ----
  {
    const float* qr = qb + y * HW;
#pragma unroll
    for (int c = 0; c < 4; ++c) {
      qv[0][c * 2 + 0] = qr[(size_t)c * PLANE + xA];
      qv[0][c * 2 + 1] = qr[(size_t)c * PLANE + xB];
    }
  }
  FENCE();
#pragma unroll
  for (int r = 0; r < 3; ++r) dma16(kb + spart[r], lds + 0 * 3072 + ldso[r]);
  FENCE();
#pragma unroll
  for (int r = 0; r < 3; ++r) dma16(kb + (size_t)4 * PLANE + spart[r], lds + 1 * 3072 + ldso[r]);
  FENCE();

#define SM(L, X) do {                                                         \
    float mk[9];                                                              \
    _Pragma("unroll")                                                         \
    for (int dy = 0; dy < 3; ++dy)                                            \
      _Pragma("unroll")                                                       \
      for (int dx = 0; dx < 3; ++dx) {                                        \
        bool ok = ((unsigned)(y + dy - 1) < (unsigned)HW) &&                  \
                  ((unsigned)((X) + dx - 1) < (unsigned)HW);                  \
        mk[dy * 3 + dx] = ok ? 1.f : 0.f;                                     \
      }                                                                       \
    float m = -1e30f;                                                         \
    _Pragma("unroll")                                                         \
    for (int i = 0; i < 9; ++i) { float t = (L)[i] * SCALE * mk[i]; (L)[i] = t; m = fmaxf(m, t); } \
    float s = 0.f;                                                            \
    _Pragma("unroll")                                                         \
    for (int i = 0; i < 9; ++i) { float e = __expf((L)[i] - m); (L)[i] = e; s += e; } \
    const float inv = 1.f / s;                                                \
    _Pragma("unroll")                                                         \
    for (int i = 0; i < 9; ++i) (L)[i] *= inv * mk[i];                        \
  } while (0)

#pragma unroll
  for (int j = 0; j < 16; ++j) {
    // ---- q prefetch for next QK chunk (group 1) ----
    if (j < 7) {
      const float* qr = qb + (size_t)((j + 1) * 4) * PLANE + y * HW;
#pragma unroll
      for (int c = 0; c < 4; ++c) {
        qv[(j + 1) & 1][c * 2 + 0] = qr[(size_t)c * PLANE + xA];
        qv[(j + 1) & 1][c * 2 + 1] = qr[(size_t)c * PLANE + xB];
      }
    }
    FENCE();
    // ---- stage job j+2, 2-deep prefetch (group 2) ----
    if (j + 2 <= 15) {
      const int nj = j + 2;
      const float* pb = (nj < 8 ? kb : vb) + (size_t)((nj & 7) * 4) * PLANE;
      float* nb = lds + (nj % 3) * 3072;
#pragma unroll
      for (int r = 0; r < 3; ++r) dma16(pb + spart[r], nb + ldso[r]);
    }
    FENCE();
    // ---- softmax once, overlapped with in-flight DMA ----
    if (j == 8) { SM(lA, xA); SM(lB, xB); }

    // ---- counted wait (ledger-derived, >=1-op margin, stores count +2) ----
    if (j < 8)        VMWAIT(10);
    else if (j == 8)  VMWAIT(4);
    else if (j < 14)  VMWAIT(6);
    else if (j == 14) VMWAIT(4);
    else              VMWAIT(2);
    __builtin_amdgcn_s_barrier();
    FENCE();

    const float* bb = lds + 4 + (j % 3) * 3072;
    if (j < 8) {
      // ---- QK: accumulate 9 logits for both pixels over this chunk ----
#pragma unroll
      for (int c = 0; c < 4; ++c) {
        const float qa = qv[j & 1][c * 2 + 0];
        const float qbv = qv[j & 1][c * 2 + 1];
        const float* rb = bb + (c * 6 + w) * HW;
#pragma unroll
        for (int dy = 0; dy < 3; ++dy) {
          const float* kr = rb + dy * HW;
          float a0 = kr[xA - 1], a1 = kr[xA], a2 = kr[xA + 1];
          float b0 = kr[xB - 1], b1 = kr[xB], b2 = kr[xB + 1];
          lA[dy * 3 + 0] += qa * a0;  lA[dy * 3 + 1] += qa * a1;  lA[dy * 3 + 2] += qa * a2;
          lB[dy * 3 + 0] += qbv * b0; lB[dy * 3 + 1] += qbv * b1; lB[dy * 3 + 2] += qbv * b2;
        }
      }
    } else {
      // ---- PV + ReLU + store this chunk's 4 channels ----
      float accA[4], accB[4];
#pragma unroll
      for (int c = 0; c < 4; ++c) { accA[c] = 0.f; accB[c] = 0.f; }
#pragma unroll
      for (int c = 0; c < 4; ++c) {
        const float* rb = bb + (c * 6 + w) * HW;
#pragma unroll
        for (int dy = 0; dy < 3; ++dy) {
          const float* vr = rb + dy * HW;
          float a0 = vr[xA - 1], a1 = vr[xA], a2 = vr[xA + 1];
          float b0 = vr[xB - 1], b1 = vr[xB], b2 = vr[xB + 1];
          accA[c] += lA[dy * 3 + 0] * a0 + lA[dy * 3 + 1] * a1 + lA[dy * 3 + 2] * a2;
          accB[c] += lB[dy * 3 + 0] * b0 + lB[dy * 3 + 1] * b1 + lB[dy * 3 + 2] * b2;
        }
      }
      const int cc = head * 32 + (j - 8) * 4;
      float* oA = out + ((size_t)(b * PLANE + y * HW + xA)) * 128 + cc;
      float* oB = out + ((size_t)(b * PLANE + y * HW + xB)) * 128 + cc;
      *reinterpret_cast<float4*>(oA) = make_float4(
          fmaxf(accA[0], 0.f), fmaxf(accA[1], 0.f), fmaxf(accA[2], 0.f), fmaxf(accA[3], 0.f));
      *reinterpret_cast<float4*>(oB) = make_float4(
          fmaxf(accB[0], 0.f), fmaxf(accB[1], 0.f), fmaxf(accB[2], 0.f), fmaxf(accB[3], 0.f));
    }
    FENCE();
    if (j < 15) __builtin_amdgcn_s_barrier();   // protect buffer re-stage
  }
#undef SM
}

extern "C" void kernel_launch(void* const* d_in, const int* in_sizes, int n_in,
                              void* d_out, int out_size, void* d_ws, size_t ws_size,
                              hipStream_t stream) {
  const float* q = (const float*)d_in[0];
  const float* k = (const float*)d_in[1];
  const float* v = (const float*)d_in[2];
  float* out = (float*)d_out;
  // grid: B(4) * heads(4) * ytiles(32) = 512 blocks, 256 threads (4 waves)
  natt3x3_kernel<<<512, 256, 0, stream>>>(q, k, v, out);
}

// Round 9
// 34.618 us; speedup vs baseline: 1.3845x; 1.3845x over previous
//
#include <hip/hip_runtime.h>

#define HW 128
#define PLANE (HW * HW)              // 16384
#define SCALE 0.17677669529663687f   // 32^-0.5
#define FENCE() asm volatile("" ::: "memory")

// R4 structure, pipelined hard (R8) + the lane-pair logit reduce R8 dropped.
// One thread = 4-pixel x-strip x 16 channels; lane = (strip<<1)|h2; wave =
// one image row; block = 4 rows. Channels per thread: g*8 + h2*4 + {0..3},
// g=0..3 (pair-contiguous 32B stores). 10 load-groups of 12-16 float4 rotated
// through 3 register buffers with asm-fence-pinned issue order so 2-3 groups
// stay in flight. No LDS, no barriers: waves fully independent.
// Grid = 4b*4h*32ytiles = 512 blocks.
__global__ __launch_bounds__(256, 2) void natt3x3_kernel(
    const float* __restrict__ q,
    const float* __restrict__ k,
    const float* __restrict__ v,
    float* __restrict__ out) {
  const int tid  = threadIdx.x;
  const int lane = tid & 63;
  const int w    = tid >> 6;            // wave index in block = row in tile
  const int h2   = lane & 1;            // channel sub-quad selector
  const int s    = lane >> 1;           // strip 0..31
  const int x0   = s << 2;              // first pixel x of strip
  const int bid  = blockIdx.x;          // ((b*4+head)*32 + ytile)
  const int ytile = bid & 31;
  const int head  = (bid >> 5) & 3;
  const int b     = bid >> 7;
  const int y     = (ytile << 2) | w;

  const size_t cbase = (size_t)(b * 128 + head * 32 + h2 * 4) * PLANE;
  const int yx = y * HW + x0;

  int yrow[3];
#pragma unroll
  for (int dy = 0; dy < 3; ++dy) {
    int yy = y + dy - 1; yy = yy < 0 ? 0 : (yy > HW - 1 ? HW - 1 : yy);
    yrow[dy] = yy * HW;
  }

  float l[4][9];
#pragma unroll
  for (int i = 0; i < 4; ++i)
#pragma unroll
    for (int j = 0; j < 9; ++j) l[i][j] = 0.f;

  float4 qv4[3][4];      // q quads per buffer
  float4 rv[3][3][4];    // k/v rows [buf][dy][c]

#define LQK(B, G) do {                                                       \
    const size_t cb = cbase + (size_t)((G) * 8) * PLANE;                     \
    const float* qg = q + cb + yx;                                           \
    const float* kg = k + cb;                                                \
    _Pragma("unroll")                                                        \
    for (int c = 0; c < 4; ++c)                                              \
      qv4[B][c] = *reinterpret_cast<const float4*>(qg + (size_t)c * PLANE);  \
    _Pragma("unroll")                                                        \
    for (int c = 0; c < 4; ++c)                                              \
      _Pragma("unroll")                                                      \
      for (int dy = 0; dy < 3; ++dy)                                         \
        rv[B][dy][c] = *reinterpret_cast<const float4*>(                     \
            kg + (size_t)c * PLANE + yrow[dy] + x0);                         \
  } while (0)

#define LPV(B, G) do {                                                       \
    const float* vg = v + cbase + (size_t)((G) * 8) * PLANE;                 \
    _Pragma("unroll")                                                        \
    for (int c = 0; c < 4; ++c)                                              \
      _Pragma("unroll")                                                      \
      for (int dy = 0; dy < 3; ++dy)                                         \
        rv[B][dy][c] = *reinterpret_cast<const float4*>(                     \
            vg + (size_t)c * PLANE + yrow[dy] + x0);                         \
  } while (0)

#define CQK(B) do {                                                          \
    _Pragma("unroll")                                                        \
    for (int c = 0; c < 4; ++c) {                                            \
      const float qa[4] = {qv4[B][c].x * SCALE, qv4[B][c].y * SCALE,         \
                           qv4[B][c].z * SCALE, qv4[B][c].w * SCALE};        \
      _Pragma("unroll")                                                      \
      for (int dy = 0; dy < 3; ++dy) {                                       \
        float4 kq = rv[B][dy][c];                                            \
        float n0 = __shfl_up(kq.w, 2);                                       \
        float n5 = __shfl_down(kq.x, 2);                                     \
        const float n[6] = {n0, kq.x, kq.y, kq.z, kq.w, n5};                 \
        _Pragma("unroll")                                                    \
        for (int i = 0; i < 4; ++i)                                          \
          _Pragma("unroll")                                                  \
          for (int j = 0; j < 3; ++j)                                        \
            l[i][dy * 3 + j] += qa[i] * n[i + j];                            \
      }                                                                      \
    }                                                                        \
  } while (0)

#define CPV(B, G) do {                                                       \
    float acc[4][4];                                                         \
    _Pragma("unroll")                                                        \
    for (int i = 0; i < 4; ++i)                                              \
      _Pragma("unroll")                                                      \
      for (int c = 0; c < 4; ++c) acc[i][c] = 0.f;                           \
    _Pragma("unroll")                                                        \
    for (int c = 0; c < 4; ++c)                                              \
      _Pragma("unroll")                                                      \
      for (int dy = 0; dy < 3; ++dy) {                                       \
        float4 vq = rv[B][dy][c];                                            \
        float n0 = __shfl_up(vq.w, 2);                                       \
        float n5 = __shfl_down(vq.x, 2);                                     \
        const float n[6] = {n0, vq.x, vq.y, vq.z, vq.w, n5};                 \
        _Pragma("unroll")                                                    \
        for (int i = 0; i < 4; ++i)                                          \
          _Pragma("unroll")                                                  \
          for (int j = 0; j < 3; ++j)                                        \
            acc[i][c] += l[i][dy * 3 + j] * n[i + j];                        \
      }                                                                      \
    _Pragma("unroll")                                                        \
    for (int i = 0; i < 4; ++i) {                                            \
      float4 o;                                                              \
      o.x = fmaxf(acc[i][0], 0.f);                                           \
      o.y = fmaxf(acc[i][1], 0.f);                                           \
      o.z = fmaxf(acc[i][2], 0.f);                                           \
      o.w = fmaxf(acc[i][3], 0.f);                                           \
      *reinterpret_cast<float4*>(out + obase + (size_t)(x0 + i) * 128 +      \
                                 (G) * 8) = o;                               \
    }                                                                        \
  } while (0)

  const size_t obase = ((size_t)(b * PLANE + y * HW)) * 128 + head * 32 + h2 * 4;

  // ---- fence-pinned schedule: 2-3 load-groups always in flight ----
  LQK(0, 0); FENCE();
  LQK(1, 1); FENCE();
  LQK(2, 2); FENCE();
  CQK(0);    FENCE();
  LQK(0, 3); FENCE();
  CQK(1);    FENCE();
  LPV(1, 0); FENCE();
  CQK(2);    FENCE();
  LPV(2, 1); FENCE();
  CQK(0);    FENCE();   // group 3
  LPV(0, 2); FENCE();

  // ---- lane-pair reduce: my 16 channels + partner's 16 = full 32 ----
  // (touches only l; the 3 in-flight PV load-groups keep flying under it)
#pragma unroll
  for (int i = 0; i < 4; ++i)
#pragma unroll
    for (int j = 0; j < 9; ++j) l[i][j] += __shfl_xor(l[i][j], 1);

  // ---- mask + softmax per pixel ----
#pragma unroll
  for (int i = 0; i < 4; ++i) {
    const int xp = x0 + i;
    float mk[9];
#pragma unroll
    for (int dy = 0; dy < 3; ++dy)
#pragma unroll
      for (int dx = 0; dx < 3; ++dx) {
        bool ok = ((unsigned)(y + dy - 1) < (unsigned)HW) &&
                  ((unsigned)(xp + dx - 1) < (unsigned)HW);
        mk[dy * 3 + dx] = ok ? 1.f : 0.f;
      }
    float m = -1e30f;
#pragma unroll
    for (int j = 0; j < 9; ++j) {
      float t = l[i][j] * mk[j];
      l[i][j] = t;
      m = fmaxf(m, t);
    }
    float sum = 0.f;
#pragma unroll
    for (int j = 0; j < 9; ++j) {
      float e = __expf(l[i][j] - m);
      l[i][j] = e;
      sum += e;
    }
    float inv = 1.f / sum;
#pragma unroll
    for (int j = 0; j < 9; ++j) l[i][j] *= inv * mk[j];
  }
  FENCE();

  CPV(1, 0); FENCE();
  LPV(1, 3); FENCE();
  CPV(2, 1); FENCE();
  CPV(0, 2); FENCE();
  CPV(1, 3);

#undef LQK
#undef LPV
#undef CQK
#undef CPV
}

extern "C" void kernel_launch(void* const* d_in, const int* in_sizes, int n_in,
                              void* d_out, int out_size, void* d_ws, size_t ws_size,
                              hipStream_t stream) {
  const float* q = (const float*)d_in[0];
  const float* k = (const float*)d_in[1];
  const float* v = (const float*)d_in[2];
  float* out = (float*)d_out;
  // grid: B(4) * heads(4) * ytiles(32) = 512 blocks, 256 threads (4 waves)
  natt3x3_kernel<<<512, 256, 0, stream>>>(q, k, v, out);
}